// Round 1
// baseline (78.961 us; speedup 1.0000x reference)
//
#include <hip/hip_runtime.h>

// Problem constants (from reference)
#define BSZ    1024   // batch
#define N_IN   1024
#define NLAYERS 5
#define NPL    2048   // nodes per layer
#define FANIN  16
#define N_OUT  256

// ---------------------------------------------------------------------------
// Kernel 1: transpose inputs (B, N_IN) row-major -> vals_t (N_IN, B)
// Standard 32x32 LDS tile transpose with +1 padding.
// ---------------------------------------------------------------------------
__global__ __launch_bounds__(1024) void transpose_in_kernel(
    const float* __restrict__ in, float* __restrict__ out)
{
    __shared__ float tile[32][33];
    int x = blockIdx.x * 32 + threadIdx.x;   // input col (node idx)
    int y = blockIdx.y * 32 + threadIdx.y;   // input row (batch)
    tile[threadIdx.y][threadIdx.x] = in[(size_t)y * N_IN + x];
    __syncthreads();
    int oy = blockIdx.x * 32 + threadIdx.y;  // output row (node idx)
    int ox = blockIdx.y * 32 + threadIdx.x;  // output col (batch)
    out[(size_t)oy * BSZ + ox] = tile[threadIdx.x][threadIdx.y];
}

// ---------------------------------------------------------------------------
// Layer kernel: one block per node, 256 threads, each thread handles 4
// consecutive batch elements (float4). Gathers from vals_t (node-major,
// batch-contiguous) are fully coalesced: per f, wave reads 64x16B = 1KB
// contiguous from row src[f].
// ACT: 0 = tanh, 1 = sigmoid. WRITE_OUT: 0 = write vals_t rows, 1 = write
// d_out (B, N_OUT) row-major (strided scalar stores; only 1 MB total).
// ---------------------------------------------------------------------------
template<int ACT, int WRITE_OUT>
__global__ __launch_bounds__(256) void layer_kernel(
    const float* __restrict__ vals_t,   // [total_prev_nodes][BSZ]
    float* __restrict__ dst,            // WRITE_OUT==0: row base; ==1: d_out
    const int* __restrict__ src,        // [NPL][FANIN] for this layer
    const float* __restrict__ w,        // [NPL][FANIN]
    const float* __restrict__ bias,     // [NPL]
    int node_base)                      // first node of this layer we compute
{
    const int n = blockIdx.x + node_base;            // node within layer
    const int* s  = src + (size_t)n * FANIN;
    const float* ww = w + (size_t)n * FANIN;
    const float bv = bias[n];

    const int b = threadIdx.x * 4;                   // batch offset
    float a0 = bv, a1 = bv, a2 = bv, a3 = bv;

#pragma unroll
    for (int f = 0; f < FANIN; ++f) {
        const int   idx = s[f];                      // wave-uniform -> scalar
        const float wf  = ww[f];
        const float4 v = *reinterpret_cast<const float4*>(
            vals_t + (size_t)idx * BSZ + b);
        a0 = fmaf(v.x, wf, a0);
        a1 = fmaf(v.y, wf, a1);
        a2 = fmaf(v.z, wf, a2);
        a3 = fmaf(v.w, wf, a3);
    }

    if (ACT == 0) {
        a0 = tanhf(a0); a1 = tanhf(a1); a2 = tanhf(a2); a3 = tanhf(a3);
    } else {
        a0 = 1.0f / (1.0f + expf(-a0));
        a1 = 1.0f / (1.0f + expf(-a1));
        a2 = 1.0f / (1.0f + expf(-a2));
        a3 = 1.0f / (1.0f + expf(-a3));
    }

    if (WRITE_OUT == 0) {
        float4 o = make_float4(a0, a1, a2, a3);
        *reinterpret_cast<float4*>(dst + (size_t)n * BSZ + b) = o;
    } else {
        // d_out is (BSZ, N_OUT) row-major; column j = blockIdx.x
        const int j = blockIdx.x;
        dst[(size_t)(b + 0) * N_OUT + j] = a0;
        dst[(size_t)(b + 1) * N_OUT + j] = a1;
        dst[(size_t)(b + 2) * N_OUT + j] = a2;
        dst[(size_t)(b + 3) * N_OUT + j] = a3;
    }
}

// ---------------------------------------------------------------------------
// Launch: transpose inputs, then 4 full tanh layers, then the final sigmoid
// layer restricted to the 256 nodes that actually reach the output.
// Workspace layout: vals_t = (N_IN + 4*NPL) rows x BSZ floats = 37.75 MB.
// (Layer 4 outputs are never gathered, so they are not stored in vals_t.)
// ---------------------------------------------------------------------------
extern "C" void kernel_launch(void* const* d_in, const int* in_sizes, int n_in,
                              void* d_out, int out_size, void* d_ws, size_t ws_size,
                              hipStream_t stream)
{
    const float* inputs   = (const float*)d_in[0];
    const int*   edge_src = (const int*)  d_in[1];
    const float* edge_w   = (const float*)d_in[2];
    const float* biases   = (const float*)d_in[3];
    float* out    = (float*)d_out;
    float* vals_t = (float*)d_ws;   // needs (1024 + 4*2048)*1024*4 B = 37.75 MB

    // inputs -> vals_t rows [0, N_IN)
    transpose_in_kernel<<<dim3(N_IN / 32, BSZ / 32), dim3(32, 32), 0, stream>>>(
        inputs, vals_t);

    // layers 0..3: full NPL nodes, tanh, write vals_t rows
    for (int l = 0; l < NLAYERS - 1; ++l) {
        layer_kernel<0, 0><<<NPL, 256, 0, stream>>>(
            vals_t,
            vals_t + (size_t)(N_IN + (size_t)l * NPL) * BSZ,
            edge_src + (size_t)l * NPL * FANIN,
            edge_w   + (size_t)l * NPL * FANIN,
            biases   + (size_t)l * NPL,
            0);
    }

    // layer 4: only last N_OUT nodes matter; sigmoid; write d_out directly
    layer_kernel<1, 1><<<N_OUT, 256, 0, stream>>>(
        vals_t,
        out,
        edge_src + (size_t)(NLAYERS - 1) * NPL * FANIN,
        edge_w   + (size_t)(NLAYERS - 1) * NPL * FANIN,
        biases   + (size_t)(NLAYERS - 1) * NPL,
        NPL - N_OUT);
}

// Round 2
// 48.367 us; speedup vs baseline: 1.6325x; 1.6325x over previous
//
#include <hip/hip_runtime.h>
#include <hip/hip_fp16.h>

// Problem constants (from reference)
#define BSZ     1024   // batch
#define N_IN    1024
#define NLAYERS 5
#define NPL     2048   // nodes per layer
#define FANIN   16
#define N_OUT   256

// ---------------------------------------------------------------------------
// Kernel 1: transpose inputs (B, N_IN) f32 row-major -> vals_t (N_IN, B) fp16
// 32x32 LDS tile transpose with +1 padding.
// ---------------------------------------------------------------------------
__global__ __launch_bounds__(1024) void transpose_in_kernel(
    const float* __restrict__ in, __half* __restrict__ out)
{
    __shared__ float tile[32][33];
    int x = blockIdx.x * 32 + threadIdx.x;   // input col (node idx)
    int y = blockIdx.y * 32 + threadIdx.y;   // input row (batch)
    tile[threadIdx.y][threadIdx.x] = in[(size_t)y * N_IN + x];
    __syncthreads();
    int oy = blockIdx.x * 32 + threadIdx.y;  // output row (node idx)
    int ox = blockIdx.y * 32 + threadIdx.x;  // output col (batch)
    out[(size_t)oy * BSZ + ox] = __float2half(tile[threadIdx.x][threadIdx.y]);
}

// ---------------------------------------------------------------------------
// Layer kernel: one block per node, 256 threads, each thread handles 4
// consecutive batch elements. Gathers from fp16 vals_t (node-major,
// batch-contiguous): per fanin f, a wave reads 64x8B = 512B contiguous from
// row src[f]. Accumulate in f32.
// ACT: 0 = tanh, 1 = sigmoid. WRITE_OUT: 0 = write fp16 vals_t row,
//                                        1 = write f32 d_out (B, N_OUT).
// ---------------------------------------------------------------------------
union H4 {
    unsigned long long u;
    __half h[4];
};

template<int ACT, int WRITE_OUT>
__global__ __launch_bounds__(256) void layer_kernel(
    const __half* __restrict__ vals_t,  // [total_prev_nodes][BSZ] fp16
    void* __restrict__ dst,             // WRITE_OUT==0: __half* rows; ==1: float* d_out
    const int* __restrict__ src,        // [NPL][FANIN] for this layer
    const float* __restrict__ w,        // [NPL][FANIN]
    const float* __restrict__ bias,     // [NPL]
    int node_base)                      // first node of this layer we compute
{
    const int n = blockIdx.x + node_base;            // node within layer
    const int* s    = src + (size_t)n * FANIN;
    const float* ww = w   + (size_t)n * FANIN;
    const float bv  = bias[n];

    const int b = threadIdx.x * 4;                   // batch offset
    float a0 = bv, a1 = bv, a2 = bv, a3 = bv;

#pragma unroll
    for (int f = 0; f < FANIN; ++f) {
        const int   idx = s[f];                      // wave-uniform -> scalar load
        const float wf  = ww[f];
        H4 v;
        v.u = *reinterpret_cast<const unsigned long long*>(
            vals_t + (size_t)idx * BSZ + b);         // 8B coalesced load
        a0 = fmaf(__half2float(v.h[0]), wf, a0);
        a1 = fmaf(__half2float(v.h[1]), wf, a1);
        a2 = fmaf(__half2float(v.h[2]), wf, a2);
        a3 = fmaf(__half2float(v.h[3]), wf, a3);
    }

    if (ACT == 0) {
        a0 = tanhf(a0); a1 = tanhf(a1); a2 = tanhf(a2); a3 = tanhf(a3);
    } else {
        a0 = 1.0f / (1.0f + __expf(-a0));
        a1 = 1.0f / (1.0f + __expf(-a1));
        a2 = 1.0f / (1.0f + __expf(-a2));
        a3 = 1.0f / (1.0f + __expf(-a3));
    }

    if (WRITE_OUT == 0) {
        H4 o;
        o.h[0] = __float2half(a0);
        o.h[1] = __float2half(a1);
        o.h[2] = __float2half(a2);
        o.h[3] = __float2half(a3);
        *reinterpret_cast<unsigned long long*>(
            (__half*)dst + (size_t)n * BSZ + b) = o.u;   // 8B store
    } else {
        // d_out is (BSZ, N_OUT) f32 row-major; column j = blockIdx.x
        float* outp = (float*)dst;
        const int j = blockIdx.x;
        outp[(size_t)(b + 0) * N_OUT + j] = a0;
        outp[(size_t)(b + 1) * N_OUT + j] = a1;
        outp[(size_t)(b + 2) * N_OUT + j] = a2;
        outp[(size_t)(b + 3) * N_OUT + j] = a3;
    }
}

// ---------------------------------------------------------------------------
// Launch: transpose inputs to fp16, 4 full tanh layers, final sigmoid layer
// restricted to the 256 nodes that reach the output (written f32 to d_out).
// Workspace: vals_t = (N_IN + 4*NPL) rows x BSZ halves = 18.9 MB.
// (Layer 4 outputs are never gathered, so they are not stored in vals_t.)
// ---------------------------------------------------------------------------
extern "C" void kernel_launch(void* const* d_in, const int* in_sizes, int n_in,
                              void* d_out, int out_size, void* d_ws, size_t ws_size,
                              hipStream_t stream)
{
    const float* inputs   = (const float*)d_in[0];
    const int*   edge_src = (const int*)  d_in[1];
    const float* edge_w   = (const float*)d_in[2];
    const float* biases   = (const float*)d_in[3];
    float*  out    = (float*)d_out;
    __half* vals_t = (__half*)d_ws;   // (1024 + 4*2048)*1024*2 B = 18.9 MB

    // inputs -> vals_t rows [0, N_IN)
    transpose_in_kernel<<<dim3(N_IN / 32, BSZ / 32), dim3(32, 32), 0, stream>>>(
        inputs, vals_t);

    // layers 0..3: full NPL nodes, tanh, write vals_t rows
    for (int l = 0; l < NLAYERS - 1; ++l) {
        layer_kernel<0, 0><<<NPL, 256, 0, stream>>>(
            vals_t,
            (void*)(vals_t + (size_t)(N_IN + (size_t)l * NPL) * BSZ),
            edge_src + (size_t)l * NPL * FANIN,
            edge_w   + (size_t)l * NPL * FANIN,
            biases   + (size_t)l * NPL,
            0);
    }

    // layer 4: only last N_OUT nodes matter; sigmoid; write d_out directly
    layer_kernel<1, 1><<<N_OUT, 256, 0, stream>>>(
        vals_t,
        (void*)out,
        edge_src + (size_t)(NLAYERS - 1) * NPL * FANIN,
        edge_w   + (size_t)(NLAYERS - 1) * NPL * FANIN,
        biases   + (size_t)(NLAYERS - 1) * NPL,
        NPL - N_OUT);
}

// Round 3
// 44.835 us; speedup vs baseline: 1.7612x; 1.0788x over previous
//
#include <hip/hip_runtime.h>
#include <hip/hip_fp16.h>

// Problem constants (from reference)
#define BSZ     1024   // batch
#define N_IN    1024
#define NLAYERS 5
#define NPL     2048   // nodes per layer
#define FANIN   16
#define N_OUT   256
#define NCHUNK  8      // batch chunks == XCD count
#define CHB     (BSZ / NCHUNK)   // 128 batch elems per chunk

// ---------------------------------------------------------------------------
// Kernel 1: transpose inputs (B, N_IN) f32 row-major -> vals_t (N_IN, B) fp16
// 32x32 LDS tile transpose; block mapping made chunk-affine (blockIdx%8 ->
// batch chunk) so layer-0 readers find their columns in the same XCD's L2.
// ---------------------------------------------------------------------------
__global__ __launch_bounds__(1024) void transpose_in_kernel(
    const float* __restrict__ in, __half* __restrict__ out)
{
    __shared__ float tile[32][33];
    const int c = blockIdx.x & 7;          // batch chunk -> XCD (heuristic)
    const int t = blockIdx.x >> 3;         // 0..127
    const int batch_tile = c * 4 + (t & 3);   // 4 tiles of 32 per 128-chunk
    const int node_tile  = t >> 2;            // 0..31

    int x = node_tile * 32 + threadIdx.x;  // input col (node idx)
    int y = batch_tile * 32 + threadIdx.y; // input row (batch)
    tile[threadIdx.y][threadIdx.x] = in[(size_t)y * N_IN + x];
    __syncthreads();
    int oy = node_tile * 32 + threadIdx.y;   // output row (node idx)
    int ox = batch_tile * 32 + threadIdx.x;  // output col (batch)
    out[(size_t)oy * BSZ + ox] = __float2half(tile[threadIdx.x][threadIdx.y]);
}

// ---------------------------------------------------------------------------
// Layer kernel: grid = (nodes/2) * 8 chunks. chunk = blockIdx&7 so a given
// batch-column range always lands on the same XCD (round-robin dispatch
// heuristic) -> per-XCD gather footprint = prev_nodes*256B <= 2.3MB, fits
// the 4MiB per-XCD L2. Block = 128 threads = 2 waves = 2 nodes x 128 batch.
// Per fanin, a wave loads 64 x 4B (__half2) = 256B contiguous.
// ACT: 0 = tanh, 1 = sigmoid. WRITE_OUT: 0 = fp16 vals_t rows, 1 = f32 d_out.
// ---------------------------------------------------------------------------
union H2 {
    unsigned int u;
    __half h[2];
};

template<int ACT, int WRITE_OUT>
__global__ __launch_bounds__(128) void layer_kernel(
    const __half* __restrict__ vals_t,  // [total_prev_nodes][BSZ] fp16
    void* __restrict__ dst,             // WRITE_OUT==0: __half* row base; ==1: float* d_out
    const int* __restrict__ src,        // [NPL][FANIN] for this layer
    const float* __restrict__ w,        // [NPL][FANIN]
    const float* __restrict__ bias,     // [NPL]
    int node_base)                      // first node of this layer we compute
{
    const int c    = blockIdx.x & 7;            // batch chunk -> XCD
    const int wave = threadIdx.x >> 6;          // 0..1: node within block
    const int lane = threadIdx.x & 63;
    const int n    = ((blockIdx.x >> 3) << 1) + wave + node_base;
    const int b    = c * CHB + (lane << 1);     // 2 batch elems per lane

    const int*   s  = src + (size_t)n * FANIN;
    const float* ww = w   + (size_t)n * FANIN;
    const float  bv = bias[n];

    float a0 = bv, a1 = bv;
#pragma unroll
    for (int f = 0; f < FANIN; ++f) {
        const int   idx = s[f];                 // wave-uniform -> scalar load
        const float wf  = ww[f];
        H2 v;
        v.u = *reinterpret_cast<const unsigned int*>(
            vals_t + (size_t)idx * BSZ + b);    // 4B coalesced load
        a0 = fmaf(__half2float(v.h[0]), wf, a0);
        a1 = fmaf(__half2float(v.h[1]), wf, a1);
    }

    if (ACT == 0) {
        a0 = tanhf(a0); a1 = tanhf(a1);
    } else {
        a0 = 1.0f / (1.0f + __expf(-a0));
        a1 = 1.0f / (1.0f + __expf(-a1));
    }

    if (WRITE_OUT == 0) {
        H2 o;
        o.h[0] = __float2half(a0);
        o.h[1] = __float2half(a1);
        *reinterpret_cast<unsigned int*>(
            (__half*)dst + (size_t)n * BSZ + b) = o.u;   // 4B store
    } else {
        // d_out is (BSZ, N_OUT) f32 row-major; column j = node offset in layer
        float* outp = (float*)dst;
        const int j = n - node_base;
        outp[(size_t)(b + 0) * N_OUT + j] = a0;
        outp[(size_t)(b + 1) * N_OUT + j] = a1;
    }
}

// ---------------------------------------------------------------------------
// Launch: transpose inputs to fp16, 4 full tanh layers, final sigmoid layer
// restricted to the 256 nodes that reach the output (written f32 to d_out).
// Workspace: vals_t = (N_IN + 4*NPL) rows x BSZ halves = 18.9 MB.
// (Layer 4 outputs are never gathered, so they are not stored in vals_t.)
// ---------------------------------------------------------------------------
extern "C" void kernel_launch(void* const* d_in, const int* in_sizes, int n_in,
                              void* d_out, int out_size, void* d_ws, size_t ws_size,
                              hipStream_t stream)
{
    const float* inputs   = (const float*)d_in[0];
    const int*   edge_src = (const int*)  d_in[1];
    const float* edge_w   = (const float*)d_in[2];
    const float* biases   = (const float*)d_in[3];
    float*  out    = (float*)d_out;
    __half* vals_t = (__half*)d_ws;   // (1024 + 4*2048)*1024*2 B = 18.9 MB

    // inputs -> vals_t rows [0, N_IN)
    transpose_in_kernel<<<1024, dim3(32, 32), 0, stream>>>(inputs, vals_t);

    // layers 0..3: full NPL nodes, tanh, write vals_t rows
    for (int l = 0; l < NLAYERS - 1; ++l) {
        layer_kernel<0, 0><<<(NPL / 2) * NCHUNK, 128, 0, stream>>>(
            vals_t,
            (void*)(vals_t + (size_t)(N_IN + (size_t)l * NPL) * BSZ),
            edge_src + (size_t)l * NPL * FANIN,
            edge_w   + (size_t)l * NPL * FANIN,
            biases   + (size_t)l * NPL,
            0);
    }

    // layer 4: only last N_OUT nodes matter; sigmoid; write d_out directly
    layer_kernel<1, 1><<<(N_OUT / 2) * NCHUNK, 128, 0, stream>>>(
        vals_t,
        (void*)out,
        edge_src + (size_t)(NLAYERS - 1) * NPL * FANIN,
        edge_w   + (size_t)(NLAYERS - 1) * NPL * FANIN,
        biases   + (size_t)(NLAYERS - 1) * NPL,
        NPL - N_OUT);
}